// Round 1
// baseline (792.120 us; speedup 1.0000x reference)
//
#include <hip/hip_runtime.h>

// SNN audio classifier, inference path.
// Structure: B=512 independent samples; one block per sample, T=100 loop in-kernel.
// All membrane state lives in LDS for the whole kernel.

#define NB 512
#define NT 100
#define LIN 686
#define C1 16
#define O1 136
#define P1 68
#define K1 13
#define S1 5
#define C2 32
#define O2 22
#define K2 7
#define S2 3
#define F1 704   // C2*O2
#define H1 32

__global__ __launch_bounds__(256) void snn_step_all(
    const float* __restrict__ x,
    const float* __restrict__ w1, const float* __restrict__ b1,
    const float* __restrict__ w2, const float* __restrict__ b2,
    const float* __restrict__ wf1, const float* __restrict__ bf1,
    const float* __restrict__ wf2, const float* __restrict__ bf2,
    float* __restrict__ out)
{
    __shared__ float sx[LIN + 2];                 // padded input row
    __shared__ float smem1[C1 * O1];              // LIF1 membrane (persistent)
    __shared__ float spool[C1 * (P1 + 2)];        // padded pooled spikes
    __shared__ float smem2[C2 * O2];              // LIF2 membrane (persistent)
    __shared__ __align__(16) float sspk2[F1];     // flattened spk2
    __shared__ float smem3[H1];
    __shared__ float sspk3[H1];
    __shared__ float smem4[2];
    __shared__ float sout[2];
    __shared__ float sw1[C1 * K1];
    __shared__ float sb1[C1];
    __shared__ float sw2[C2 * C1 * K2];
    __shared__ float sb2[C2];
    __shared__ float sbf1[H1];
    __shared__ float swf2[2 * H1];
    __shared__ float sbf2[2];

    const int tid = threadIdx.x;
    const int b = blockIdx.x;

    // ---- init persistent state + weights ----
    for (int i = tid; i < C1 * O1; i += 256) smem1[i] = 0.f;
    for (int i = tid; i < C1 * (P1 + 2); i += 256) spool[i] = 0.f;   // pads stay 0 forever
    for (int i = tid; i < C2 * O2; i += 256) smem2[i] = 0.f;
    for (int i = tid; i < C1 * K1; i += 256) sw1[i] = w1[i];
    for (int i = tid; i < C2 * C1 * K2; i += 256) sw2[i] = w2[i];
    if (tid < C1) sb1[tid] = b1[tid];
    if (tid < C2) sb2[tid] = b2[tid];
    if (tid < H1) { sbf1[tid] = bf1[tid]; smem3[tid] = 0.f; }
    if (tid < 2 * H1) swf2[tid] = wf2[tid];
    if (tid < 2) { sbf2[tid] = bf2[tid]; smem4[tid] = 0.f; sout[tid] = 0.f; }
    if (tid == 0) { sx[0] = 0.f; sx[LIN + 1] = 0.f; }
    __syncthreads();

    const float* xb = x + (size_t)b * NT * LIN;

    for (int t = 0; t < NT; ++t) {
        // ---- load x_t into padded LDS row ----
        const float* xt = xb + t * LIN;
        for (int i = tid; i < LIN; i += 256) sx[i + 1] = xt[i];
        __syncthreads();

        // ---- phase A: conv1 (k=13,s=5,p=1) + LIF1 + maxpool2, fused ----
        // one item = one pooled output (c,p); computes conv outputs 2p,2p+1
        for (int item = tid; item < C1 * P1; item += 256) {
            int c = item / P1, p = item - c * P1;
            int o0 = 2 * p;
            const float* wr = &sw1[c * K1];
            const float* x0 = &sx[o0 * S1];
            float a0 = 0.f, a1 = 0.f;
            #pragma unroll
            for (int k = 0; k < K1; ++k) {
                float w = wr[k];
                a0 += w * x0[k];
                a1 += w * x0[k + S1];   // overlapping window: compiler CSEs x reads
            }
            float bias = sb1[c];
            float cur0 = a0 + bias, cur1 = a1 + bias;
            int mi = c * O1 + o0;
            float m0 = smem1[mi], m1 = smem1[mi + 1];
            float r0 = (m0 > 1.0f) ? 1.0f : 0.0f;
            float r1 = (m1 > 1.0f) ? 1.0f : 0.0f;
            m0 = 0.9f * m0 + cur0 - r0;
            m1 = 0.9f * m1 + cur1 - r1;
            smem1[mi] = m0; smem1[mi + 1] = m1;
            spool[c * (P1 + 2) + p + 1] = (m0 > 1.0f || m1 > 1.0f) ? 1.0f : 0.0f;
        }
        __syncthreads();

        // ---- phase B: conv2 (k=7,s=3,p=1) + LIF2 ----
        // one item = (c, output-pair): share w reads across o0,o1; CSE pool reads
        for (int item = tid; item < C2 * (O2 / 2); item += 256) {
            int c = item / (O2 / 2), op = item - c * (O2 / 2);
            int o0 = 2 * op;
            float a0 = 0.f, a1 = 0.f;
            const float* wr = &sw2[c * C1 * K2];
            #pragma unroll
            for (int i = 0; i < C1; ++i) {
                const float* pr = &spool[i * (P1 + 2) + o0 * S2];
                const float* wk = &wr[i * K2];
                #pragma unroll
                for (int k = 0; k < K2; ++k) {
                    float w = wk[k];
                    a0 += w * pr[k];
                    a1 += w * pr[k + S2];
                }
            }
            float bias = sb2[c];
            int i0 = c * O2 + o0;
            float cur0 = a0 + bias, cur1 = a1 + bias;
            float m0 = smem2[i0], m1 = smem2[i0 + 1];
            float r0 = (m0 > 1.0f) ? 1.0f : 0.0f;
            float r1 = (m1 > 1.0f) ? 1.0f : 0.0f;
            m0 = 0.9f * m0 + cur0 - r0;
            m1 = 0.9f * m1 + cur1 - r1;
            smem2[i0] = m0; smem2[i0 + 1] = m1;
            sspk2[i0]     = (m0 > 1.0f) ? 1.0f : 0.0f;
            sspk2[i0 + 1] = (m1 > 1.0f) ? 1.0f : 0.0f;
        }
        __syncthreads();

        // ---- phase C: fc1 (704->32) + LIF3; 8 threads per output row ----
        {
            int j = tid >> 3, sub = tid & 7;           // j in [0,32), sub in [0,8)
            const float4* wr = reinterpret_cast<const float4*>(wf1 + j * F1 + sub * 88);
            const float4* sp = reinterpret_cast<const float4*>(&sspk2[sub * 88]);
            float acc = 0.f;
            #pragma unroll
            for (int i = 0; i < 22; ++i) {
                float4 w = wr[i];
                float4 s = sp[i];
                acc += w.x * s.x + w.y * s.y + w.z * s.z + w.w * s.w;
            }
            acc += __shfl_down(acc, 4, 8);
            acc += __shfl_down(acc, 2, 8);
            acc += __shfl_down(acc, 1, 8);
            if (sub == 0) {
                float cur = acc + sbf1[j];
                float m = smem3[j];
                float r = (m > 1.0f) ? 1.0f : 0.0f;
                m = 0.9f * m + cur - r;
                smem3[j] = m;
                sspk3[j] = (m > 1.0f) ? 1.0f : 0.0f;
            }
        }
        __syncthreads();

        // ---- phase D: fc2 (32->2) + LIF4 + spike count ----
        if (tid < 2) {
            float acc = 0.f;
            #pragma unroll
            for (int i = 0; i < H1; ++i) acc += sspk3[i] * swf2[tid * H1 + i];
            float cur = acc + sbf2[tid];
            float m = smem4[tid];
            float r = (m > 1.0f) ? 1.0f : 0.0f;
            m = 0.9f * m + cur - r;
            smem4[tid] = m;
            if (m > 1.0f) sout[tid] += 1.0f;
        }
        __syncthreads();
    }

    if (tid < 2) out[b * 2 + tid] = sout[tid];
}

extern "C" void kernel_launch(void* const* d_in, const int* in_sizes, int n_in,
                              void* d_out, int out_size, void* d_ws, size_t ws_size,
                              hipStream_t stream) {
    const float* x   = (const float*)d_in[0];
    const float* w1  = (const float*)d_in[1];
    const float* b1  = (const float*)d_in[2];
    const float* w2  = (const float*)d_in[3];
    const float* b2  = (const float*)d_in[4];
    const float* wf1 = (const float*)d_in[5];
    const float* bf1 = (const float*)d_in[6];
    const float* wf2 = (const float*)d_in[7];
    const float* bf2 = (const float*)d_in[8];
    float* out = (float*)d_out;

    snn_step_all<<<NB, 256, 0, stream>>>(x, w1, b1, w2, b2, wf1, bf1, wf2, bf2, out);
}